// Round 2
// baseline (13311.815 us; speedup 1.0000x reference)
//
#include <hip/hip_runtime.h>

// ---------------------------------------------------------------------------
// T5 backbone forward, round 1: all tensors fp32 (per reference dtypes).
//   - generic tiled vector-ALU GEMM (128x64 block tile, 8x4 per thread)
//   - attention: QK^T(+scale+mask) -> softmax -> PV, per-batch score buffer
//   - fused residual+LayerNorm; gelu_new elementwise
// Workspace: 9 x 2M floats + 4M (scores) + 8M (FFN) = 120 MiB.
// ---------------------------------------------------------------------------

#define LNUM 6
#define HDIM 1024
#define NHEAD 16
#define DHEAD 64
#define BDIM 4
#define SDIM 512
#define FDIM 4096
#define MROWS (BDIM * SDIM)   // 2048

// ---------------------------------------------------------------------------
// Generic GEMM: C[M,N] = A[M,K] @ W[K,N] + bias   (all fp32, ldw == N)
// Block tile 128x64, K-tile 16, 256 threads, thread tile 8x4.
// ---------------------------------------------------------------------------
#define GM 128
#define GN 64
#define GK 16

__global__ __launch_bounds__(256) void gemm_kernel(
    const float* __restrict__ A, const float* __restrict__ W,
    const float* __restrict__ bias, float* __restrict__ C,
    int M, int N, int K)
{
    __shared__ float As[GK][GM];   // transposed A tile: As[k][m]
    __shared__ float Ws[GK][GN];

    const int t = threadIdx.x;
    const int row0 = blockIdx.x * GM;
    const int col0 = blockIdx.y * GN;
    const int tn = (t & 15) * 4;   // 0..60
    const int tm = (t >> 4) * 8;   // 0..120

    float acc[8][4];
#pragma unroll
    for (int i = 0; i < 8; ++i)
#pragma unroll
        for (int j = 0; j < 4; ++j) acc[i][j] = 0.0f;

    for (int k0 = 0; k0 < K; k0 += GK) {
        // A tile: 128x16 = 2048 floats, 8 per thread (2 x float4)
#pragma unroll
        for (int l = 0; l < 2; ++l) {
            int idx = t + l * 256;          // 0..511
            int r = idx >> 2;               // 0..127
            int kq = (idx & 3) * 4;         // 0,4,8,12
            const float4 a4 = *(const float4*)(A + (size_t)(row0 + r) * K + k0 + kq);
            As[kq + 0][r] = a4.x;
            As[kq + 1][r] = a4.y;
            As[kq + 2][r] = a4.z;
            As[kq + 3][r] = a4.w;
        }
        // W tile: 16x64 fp32, 4 per thread
        {
            int kk = t >> 4;                // 0..15
            int c = (t & 15) * 4;
            const float4 w4 = *(const float4*)(W + (size_t)(k0 + kk) * N + col0 + c);
            Ws[kk][c + 0] = w4.x;
            Ws[kk][c + 1] = w4.y;
            Ws[kk][c + 2] = w4.z;
            Ws[kk][c + 3] = w4.w;
        }
        __syncthreads();
#pragma unroll
        for (int kk = 0; kk < GK; ++kk) {
            float a[8], w[4];
            *(float4*)&a[0] = *(const float4*)&As[kk][tm];
            *(float4*)&a[4] = *(const float4*)&As[kk][tm + 4];
            *(float4*)&w[0] = *(const float4*)&Ws[kk][tn];
#pragma unroll
            for (int i = 0; i < 8; ++i)
#pragma unroll
                for (int j = 0; j < 4; ++j)
                    acc[i][j] = fmaf(a[i], w[j], acc[i][j]);
        }
        __syncthreads();
    }

    const float b0 = bias[col0 + tn + 0];
    const float b1 = bias[col0 + tn + 1];
    const float b2 = bias[col0 + tn + 2];
    const float b3 = bias[col0 + tn + 3];
#pragma unroll
    for (int i = 0; i < 8; ++i) {
        float4 o;
        o.x = acc[i][0] + b0;
        o.y = acc[i][1] + b1;
        o.z = acc[i][2] + b2;
        o.w = acc[i][3] + b3;
        *(float4*)(C + (size_t)(row0 + tm + i) * N + col0 + tn) = o;
    }
}

// ---------------------------------------------------------------------------
// QK^T with scale + additive mask. One batch b; grid (NH, S/32).
// scores (per-batch buffer): [NH, S, S]
// ---------------------------------------------------------------------------
__global__ __launch_bounds__(256) void qk_kernel(
    const float* __restrict__ q, const float* __restrict__ k,
    const int* __restrict__ mask, float* __restrict__ scores, int b)
{
    const int n = blockIdx.x;
    const int r0 = blockIdx.y * 32;
    const int t = threadIdx.x;

    __shared__ float qs[32][64];
    __shared__ float ks[64][65];   // padded: compute reads are lane-varying in first idx

    // load 32 q rows for head n
#pragma unroll
    for (int l = 0; l < 2; ++l) {
        int idx = t + l * 256;           // 0..511
        int r = idx >> 4;                // 0..31
        int dq = (idx & 15) * 4;
        const float4 v4 = *(const float4*)(
            q + (((size_t)b * SDIM + r0 + r) * HDIM) + n * DHEAD + dq);
        *(float4*)&qs[r][dq] = v4;
    }

    const int c = t & 63;
    const int rg = t >> 6;               // 0..3

    for (int j0 = 0; j0 < SDIM; j0 += 64) {
#pragma unroll
        for (int l = 0; l < 4; ++l) {
            int idx = t + l * 256;       // 0..1023
            int jj = idx >> 4;           // 0..63
            int dq = (idx & 15) * 4;
            const float4 v4 = *(const float4*)(
                k + (((size_t)b * SDIM + j0 + jj) * HDIM) + n * DHEAD + dq);
            ks[jj][dq + 0] = v4.x;
            ks[jj][dq + 1] = v4.y;
            ks[jj][dq + 2] = v4.z;
            ks[jj][dq + 3] = v4.w;
        }
        __syncthreads();

        float s[8];
#pragma unroll
        for (int r = 0; r < 8; ++r) s[r] = 0.0f;
#pragma unroll 8
        for (int d = 0; d < 64; ++d) {
            float kv = ks[c][d];
#pragma unroll
            for (int r = 0; r < 8; ++r)
                s[r] = fmaf(qs[rg * 8 + r][d], kv, s[r]);
        }
        float add = (1.0f - (float)mask[b * SDIM + j0 + c]) * -10000.0f;
#pragma unroll
        for (int r = 0; r < 8; ++r) {
            int row = r0 + rg * 8 + r;
            scores[((size_t)n * SDIM + row) * SDIM + j0 + c] = s[r] * 0.125f + add;
        }
        __syncthreads();
    }
}

// ---------------------------------------------------------------------------
// Row softmax in place. grid = NH*S over the per-batch score buffer.
// ---------------------------------------------------------------------------
__global__ __launch_bounds__(256) void softmax_kernel(float* __restrict__ scores)
{
    float* p = scores + (size_t)blockIdx.x * SDIM;
    const int t = threadIdx.x;
    __shared__ float red[4];

    float a0 = p[t], a1 = p[t + 256];
    float m = fmaxf(a0, a1);
#pragma unroll
    for (int off = 32; off > 0; off >>= 1) m = fmaxf(m, __shfl_down(m, off, 64));
    if ((t & 63) == 0) red[t >> 6] = m;
    __syncthreads();
    m = fmaxf(fmaxf(red[0], red[1]), fmaxf(red[2], red[3]));

    float e0 = __expf(a0 - m), e1 = __expf(a1 - m);
    float s = e0 + e1;
#pragma unroll
    for (int off = 32; off > 0; off >>= 1) s += __shfl_down(s, off, 64);
    __syncthreads();                     // red reads (max phase) done
    if ((t & 63) == 0) red[t >> 6] = s;
    __syncthreads();
    s = red[0] + red[1] + red[2] + red[3];

    float inv = 1.0f / s;
    p[t] = e0 * inv;
    p[t + 256] = e1 * inv;
}

// ---------------------------------------------------------------------------
// PV: ctx[b,i,n,d] = sum_j prob[n,i,j] * v[b,j,n,d]. grid (NH, S/32).
// ---------------------------------------------------------------------------
__global__ __launch_bounds__(256) void pv_kernel(
    const float* __restrict__ prob, const float* __restrict__ v,
    float* __restrict__ ctx, int b)
{
    const int n = blockIdx.x;
    const int r0 = blockIdx.y * 32;
    const int t = threadIdx.x;

    __shared__ float vs[64][64];
    __shared__ float ps[32][64];

    const int d = t & 63;
    const int rg = t >> 6;

    float acc[8];
#pragma unroll
    for (int r = 0; r < 8; ++r) acc[r] = 0.0f;

    for (int j0 = 0; j0 < SDIM; j0 += 64) {
#pragma unroll
        for (int l = 0; l < 4; ++l) {
            int idx = t + l * 256;
            int jj = idx >> 4;
            int dq = (idx & 15) * 4;
            *(float4*)&vs[jj][dq] = *(const float4*)(
                v + (((size_t)b * SDIM + j0 + jj) * HDIM) + n * DHEAD + dq);
        }
#pragma unroll
        for (int l = 0; l < 2; ++l) {
            int idx = t + l * 256;
            int r = idx >> 4;            // 0..31
            int jq = (idx & 15) * 4;
            *(float4*)&ps[r][jq] = *(const float4*)(
                prob + ((size_t)n * SDIM + r0 + r) * SDIM + j0 + jq);
        }
        __syncthreads();
#pragma unroll 8
        for (int jj = 0; jj < 64; ++jj) {
            float vv = vs[jj][d];
#pragma unroll
            for (int r = 0; r < 8; ++r)
                acc[r] = fmaf(ps[rg * 8 + r][jj], vv, acc[r]);
        }
        __syncthreads();
    }
#pragma unroll
    for (int r = 0; r < 8; ++r) {
        int row = r0 + rg * 8 + r;
        ctx[(((size_t)b * SDIM + row) * HDIM) + n * DHEAD + d] = acc[r];
    }
}

// ---------------------------------------------------------------------------
// Fused residual + LayerNorm: out = LN(x + resid) * gamma + beta
// ln: [2, H] fp32 (gamma, beta). grid = MROWS, 256 threads, 4 elems/thread.
// ---------------------------------------------------------------------------
__global__ __launch_bounds__(256) void ln_kernel(
    const float* __restrict__ x, const float* __restrict__ resid,
    const float* __restrict__ ln, float* __restrict__ out)
{
    const int row = blockIdx.x;
    const float* xr = x + (size_t)row * HDIM;
    const float* rr = resid + (size_t)row * HDIM;
    const int t = threadIdx.x;
    __shared__ float red[4];

    float z[4];
    float s = 0.0f;
#pragma unroll
    for (int i = 0; i < 4; ++i) {
        int c = t + i * 256;
        z[i] = xr[c] + rr[c];
        s += z[i];
    }
#pragma unroll
    for (int off = 32; off > 0; off >>= 1) s += __shfl_down(s, off, 64);
    if ((t & 63) == 0) red[t >> 6] = s;
    __syncthreads();
    s = red[0] + red[1] + red[2] + red[3];
    float mean = s * (1.0f / (float)HDIM);

    float vs = 0.0f;
#pragma unroll
    for (int i = 0; i < 4; ++i) {
        float d = z[i] - mean;
        vs += d * d;
    }
#pragma unroll
    for (int off = 32; off > 0; off >>= 1) vs += __shfl_down(vs, off, 64);
    __syncthreads();                     // red reads (mean phase) done
    if ((t & 63) == 0) red[t >> 6] = vs;
    __syncthreads();
    vs = red[0] + red[1] + red[2] + red[3];
    float inv = rsqrtf(vs * (1.0f / (float)HDIM) + 1e-12f);

#pragma unroll
    for (int i = 0; i < 4; ++i) {
        int c = t + i * 256;
        out[(size_t)row * HDIM + c] = (z[i] - mean) * inv * ln[c] + ln[HDIM + c];
    }
}

// ---------------------------------------------------------------------------
// gelu_new elementwise in place
// ---------------------------------------------------------------------------
__global__ __launch_bounds__(256) void gelu_kernel(float* __restrict__ p, int n)
{
    int i = blockIdx.x * 256 + threadIdx.x;
    if (i < n) {
        float x = p[i];
        float u = 0.7978845608028654f * (x + 0.044715f * x * x * x);
        p[i] = 0.5f * x * (1.0f + tanhf(u));
    }
}

// ---------------------------------------------------------------------------
// fp32 copy (float4)
// ---------------------------------------------------------------------------
__global__ __launch_bounds__(256) void copy4_kernel(
    const float* __restrict__ in, float* __restrict__ out, int n4)
{
    int i = blockIdx.x * 256 + threadIdx.x;
    if (i < n4) ((float4*)out)[i] = ((const float4*)in)[i];
}

// ---------------------------------------------------------------------------
extern "C" void kernel_launch(void* const* d_in, const int* in_sizes, int n_in,
                              void* d_out, int out_size, void* d_ws, size_t ws_size,
                              hipStream_t stream)
{
    const float* in_hidden = (const float*)d_in[0];
    const float* enc       = (const float*)d_in[1];   // used directly (read-only)
    const int* attn_mask   = (const int*)d_in[2];
    const int* enc_attn_mask = (const int*)d_in[3];
    const float* sa_qkv_w  = (const float*)d_in[4];
    const float* sa_qkv_b  = (const float*)d_in[5];
    const float* sa_out_w  = (const float*)d_in[6];
    const float* sa_out_b  = (const float*)d_in[7];
    const float* sa_ln     = (const float*)d_in[8];
    const float* ca_qkv_w  = (const float*)d_in[9];
    const float* ca_qkv_b  = (const float*)d_in[10];
    const float* ca_out_w  = (const float*)d_in[11];
    const float* ca_out_b  = (const float*)d_in[12];
    const float* ca_ln     = (const float*)d_in[13];
    const float* o1_w      = (const float*)d_in[14];
    const float* o1_b      = (const float*)d_in[15];
    const float* o1_ln     = (const float*)d_in[16];
    const float* ffn_w     = (const float*)d_in[17];
    const float* ffn_b     = (const float*)d_in[18];
    const float* o2_w      = (const float*)d_in[19];
    const float* o2_b      = (const float*)d_in[20];
    const float* o2_ln     = (const float*)d_in[21];

    const size_t MH = (size_t)MROWS * HDIM;           // 2M floats
    float* ws = (float*)d_ws;
    float* h      = ws;                   // 2M
    float* qb     = h + MH;               // 2M
    float* kb     = qb + MH;              // 2M
    float* vb     = kb + MH;              // 2M
    float* ctx    = vb + MH;              // 2M
    float* t2     = ctx + MH;             // 2M
    float* attn1  = t2 + MH;              // 2M
    float* crossb = attn1 + MH;           // 2M
    float* attn2  = crossb + MH;          // 2M
    float* scores = attn2 + MH;           // NH*S*S = 4M (per-batch reuse)
    float* tmp8   = scores + (size_t)NHEAD * SDIM * SDIM;  // M*F = 8M
    // total: 9*2M + 4M + 8M = 30M floats = 120 MiB

    const int nElemH = MROWS * HDIM;      // 2,097,152

    copy4_kernel<<<(nElemH / 4 + 255) / 256, 256, 0, stream>>>(in_hidden, h, nElemH / 4);

    auto gemm = [&](const float* A, const float* W, const float* bias,
                    float* C, int M, int N, int K) {
        dim3 grid(M / GM, N / GN);
        gemm_kernel<<<grid, 256, 0, stream>>>(A, W, bias, C, M, N, K);
    };

    const size_t Hsq = (size_t)HDIM * HDIM;

    for (int l = 0; l < LNUM; ++l) {
        // ---- self attention ----
        gemm(h, sa_qkv_w + ((size_t)l * 3 + 0) * Hsq, sa_qkv_b + ((size_t)l * 3 + 0) * HDIM,
             qb, MROWS, HDIM, HDIM);
        gemm(h, sa_qkv_w + ((size_t)l * 3 + 1) * Hsq, sa_qkv_b + ((size_t)l * 3 + 1) * HDIM,
             kb, MROWS, HDIM, HDIM);
        gemm(h, sa_qkv_w + ((size_t)l * 3 + 2) * Hsq, sa_qkv_b + ((size_t)l * 3 + 2) * HDIM,
             vb, MROWS, HDIM, HDIM);
        for (int b = 0; b < BDIM; ++b) {
            qk_kernel<<<dim3(NHEAD, SDIM / 32), 256, 0, stream>>>(qb, kb, attn_mask, scores, b);
            softmax_kernel<<<NHEAD * SDIM, 256, 0, stream>>>(scores);
            pv_kernel<<<dim3(NHEAD, SDIM / 32), 256, 0, stream>>>(scores, vb, ctx, b);
        }
        gemm(ctx, sa_out_w + (size_t)l * Hsq, sa_out_b + (size_t)l * HDIM, t2, MROWS, HDIM, HDIM);
        ln_kernel<<<MROWS, 256, 0, stream>>>(t2, h, sa_ln + (size_t)l * 2 * HDIM, attn1);

        // ---- cross attention (residual is h) ----
        gemm(h,   ca_qkv_w + ((size_t)l * 3 + 0) * Hsq, ca_qkv_b + ((size_t)l * 3 + 0) * HDIM,
             qb, MROWS, HDIM, HDIM);
        gemm(enc, ca_qkv_w + ((size_t)l * 3 + 1) * Hsq, ca_qkv_b + ((size_t)l * 3 + 1) * HDIM,
             kb, MROWS, HDIM, HDIM);
        gemm(enc, ca_qkv_w + ((size_t)l * 3 + 2) * Hsq, ca_qkv_b + ((size_t)l * 3 + 2) * HDIM,
             vb, MROWS, HDIM, HDIM);
        for (int b = 0; b < BDIM; ++b) {
            qk_kernel<<<dim3(NHEAD, SDIM / 32), 256, 0, stream>>>(qb, kb, enc_attn_mask, scores, b);
            softmax_kernel<<<NHEAD * SDIM, 256, 0, stream>>>(scores);
            pv_kernel<<<dim3(NHEAD, SDIM / 32), 256, 0, stream>>>(scores, vb, ctx, b);
        }
        gemm(ctx, ca_out_w + (size_t)l * Hsq, ca_out_b + (size_t)l * HDIM, t2, MROWS, HDIM, HDIM);
        ln_kernel<<<MROWS, 256, 0, stream>>>(t2, h, ca_ln + (size_t)l * 2 * HDIM, crossb);

        // ---- output_1: LN(attn1 @ o1_w + o1_b + cross) ----
        gemm(attn1, o1_w + (size_t)l * Hsq, o1_b + (size_t)l * HDIM, t2, MROWS, HDIM, HDIM);
        ln_kernel<<<MROWS, 256, 0, stream>>>(t2, crossb, o1_ln + (size_t)l * 2 * HDIM, attn2);

        // ---- FFN ----
        gemm(attn2, ffn_w + (size_t)l * HDIM * FDIM, ffn_b + (size_t)l * FDIM,
             tmp8, MROWS, FDIM, HDIM);
        {
            int n = MROWS * FDIM;
            gelu_kernel<<<(n + 255) / 256, 256, 0, stream>>>(tmp8, n);
        }
        gemm(tmp8, o2_w + (size_t)l * FDIM * HDIM, o2_b + (size_t)l * HDIM, t2, MROWS, HDIM, FDIM);
        float* dst = (l == LNUM - 1) ? (float*)d_out : h;
        ln_kernel<<<MROWS, 256, 0, stream>>>(t2, attn2, o2_ln + (size_t)l * 2 * HDIM, dst);
    }
}

// Round 3
// 5896.892 us; speedup vs baseline: 2.2574x; 2.2574x over previous
//
#include <hip/hip_runtime.h>

// ---------------------------------------------------------------------------
// T5 backbone forward, round 2: bf16 MFMA GEMMs (m97 structure).
//  - per-layer weight convert+transpose fp32[K][N] -> bf16[N][K] in ws
//  - activations bf16 at producers (LN / PV / gelu epilogue), fp32 accumulate
//  - GEMM: 128xBN tile, BK=64, global_load_lds 16B staging, 16x16x32 bf16 MFMA
//  - attention QK/softmax/PV still fp32 vector (next round: flash + MFMA)
// ---------------------------------------------------------------------------

#define LNUM 6
#define HDIM 1024
#define NHEAD 16
#define DHEAD 64
#define BDIM 4
#define SDIM 512
#define FDIM 4096
#define MROWS (BDIM * SDIM)   // 2048

typedef __bf16 bf16_t;
typedef bf16_t bf16x8 __attribute__((ext_vector_type(8)));
typedef float f32x4 __attribute__((ext_vector_type(4)));
typedef unsigned short ushort_t;

__device__ __forceinline__ float bf2f(unsigned short u) {
    union { unsigned int i; float f; } x;
    x.i = ((unsigned int)u) << 16;
    return x.f;
}

__device__ __forceinline__ unsigned short f2bf(float f) {
    union { float f; unsigned int i; } u;
    u.f = f;
    unsigned int x = u.i;
    unsigned int lsb = (x >> 16) & 1u;
    x += 0x7fffu + lsb;           // round-to-nearest-even
    return (unsigned short)(x >> 16);
}

// async global->LDS, 16 bytes per lane; lds dest = wave-uniform base + lane*16
__device__ __forceinline__ void async16(const unsigned short* g, unsigned short* l) {
    __builtin_amdgcn_global_load_lds(
        (const __attribute__((address_space(1))) unsigned int*)g,
        (__attribute__((address_space(3))) unsigned int*)l, 16, 0, 0);
}

// ---------------------------------------------------------------------------
// MFMA GEMM: C[M,N] = A[M,K](bf16) @ BT[N,K](bf16)^T + bias(f32)
// BM=128, BK=64, 256 threads (4 waves as 2x2), per-wave 64 x BN/2 output.
// ---------------------------------------------------------------------------
template<int BN, bool GELU, bool OUTBF16>
__global__ __launch_bounds__(256) void mfma_gemm(
    const unsigned short* __restrict__ A,
    const unsigned short* __restrict__ BT,
    const float* __restrict__ bias,
    void* __restrict__ Cv,
    int M, int N, int K)
{
    constexpr int BM = 128;
    constexpr int BK = 64;
    constexpr int MI = 4;             // 4 m-frags of 16
    constexpr int NJ = BN / 32;       // n-frags per wave

    __shared__ unsigned short As[BM][BK];
    __shared__ unsigned short Bs[BN][BK];

    const int t = threadIdx.x;
    const int w = t >> 6;
    const int lane = t & 63;
    const int quad = lane >> 4;
    const int cm = lane & 15;
    const int wrow = (w >> 1) * 64;
    const int wcol = (w & 1) * (BN / 2);
    const int row0 = blockIdx.x * BM;
    const int col0 = blockIdx.y * BN;

    f32x4 acc[MI][NJ] = {};

    const int lrow = lane >> 3;            // 0..7
    const int lcol = (lane & 7) * 8;       // 0..56

    for (int k0 = 0; k0 < K; k0 += BK) {
        // stage A: 16 rows of 8 per instr; wave w covers m = w*32 .. +31
#pragma unroll
        for (int j = 0; j < 4; ++j) {
            int mb = w * 32 + j * 8;
            async16(A + (size_t)(row0 + mb + lrow) * K + k0 + lcol, &As[mb][0]);
        }
        // stage BT rows (n-major)
#pragma unroll
        for (int j = 0; j < NJ; ++j) {
            int nb = w * (BN / 4) + j * 8;
            async16(BT + (size_t)(col0 + nb + lrow) * K + k0 + lcol, &Bs[nb][0]);
        }
        __syncthreads();

#pragma unroll
        for (int kk = 0; kk < BK; kk += 32) {
            bf16x8 av[MI], bv[NJ];
#pragma unroll
            for (int i = 0; i < MI; ++i)
                av[i] = *(const bf16x8*)&As[wrow + 16 * i + cm][kk + quad * 8];
#pragma unroll
            for (int j = 0; j < NJ; ++j)
                bv[j] = *(const bf16x8*)&Bs[wcol + 16 * j + cm][kk + quad * 8];
#pragma unroll
            for (int i = 0; i < MI; ++i)
#pragma unroll
                for (int j = 0; j < NJ; ++j)
                    acc[i][j] = __builtin_amdgcn_mfma_f32_16x16x32_bf16(
                        av[i], bv[j], acc[i][j], 0, 0, 0);
        }
        __syncthreads();
    }

    // epilogue: C/D layout col=lane&15, row=quad*4+reg
#pragma unroll
    for (int j = 0; j < NJ; ++j) {
        int col = col0 + wcol + 16 * j + cm;
        float bb = bias[col];
#pragma unroll
        for (int i = 0; i < MI; ++i) {
#pragma unroll
            for (int r = 0; r < 4; ++r) {
                int row = row0 + wrow + 16 * i + quad * 4 + r;
                float c = acc[i][j][r] + bb;
                if (GELU) {
                    float u = 0.7978845608028654f * (c + 0.044715f * c * c * c);
                    c = 0.5f * c * (1.0f + tanhf(u));
                }
                if (OUTBF16)
                    ((unsigned short*)Cv)[(size_t)row * N + col] = f2bf(c);
                else
                    ((float*)Cv)[(size_t)row * N + col] = c;
            }
        }
    }
}

// ---------------------------------------------------------------------------
// Weight convert + transpose: in fp32 [K][N] -> out bf16 [N][K]. 64x64 tiles.
// grid (N/64, K/64, nmat) for stacked contiguous matrices.
// ---------------------------------------------------------------------------
__global__ __launch_bounds__(256) void convtrans_kernel(
    const float* __restrict__ in, unsigned short* __restrict__ out, int K, int N)
{
    __shared__ unsigned short tile[64][72];   // [n][k], stride 72 keeps 16B align
    const size_t moff = (size_t)blockIdx.z * K * N;
    const int n0 = blockIdx.x * 64, k0 = blockIdx.y * 64;
    const int t = threadIdx.x;
#pragma unroll
    for (int l = 0; l < 4; ++l) {
        int idx = t + l * 256;           // 0..1023
        int kk = idx >> 4;               // 0..63
        int nn = (idx & 15) * 4;
        float4 v = *(const float4*)(in + moff + (size_t)(k0 + kk) * N + n0 + nn);
        tile[nn + 0][kk] = f2bf(v.x);
        tile[nn + 1][kk] = f2bf(v.y);
        tile[nn + 2][kk] = f2bf(v.z);
        tile[nn + 3][kk] = f2bf(v.w);
    }
    __syncthreads();
#pragma unroll
    for (int l = 0; l < 2; ++l) {
        int c = t + l * 256;             // 0..511
        int nn = c >> 3;
        int kk = (c & 7) * 8;
        *(uint4*)(out + moff + (size_t)(n0 + nn) * K + k0 + kk) =
            *(const uint4*)&tile[nn][kk];
    }
}

// ---------------------------------------------------------------------------
// QK^T with scale + mask (fp32). One batch b; grid (NH, S/32).
// ---------------------------------------------------------------------------
__global__ __launch_bounds__(256) void qk_kernel(
    const float* __restrict__ q, const float* __restrict__ k,
    const int* __restrict__ mask, float* __restrict__ scores, int b)
{
    const int n = blockIdx.x;
    const int r0 = blockIdx.y * 32;
    const int t = threadIdx.x;

    __shared__ float qs[32][64];
    __shared__ float ks[64][65];

#pragma unroll
    for (int l = 0; l < 2; ++l) {
        int idx = t + l * 256;
        int r = idx >> 4;
        int dq = (idx & 15) * 4;
        *(float4*)&qs[r][dq] = *(const float4*)(
            q + (((size_t)b * SDIM + r0 + r) * HDIM) + n * DHEAD + dq);
    }

    const int c = t & 63;
    const int rg = t >> 6;

    for (int j0 = 0; j0 < SDIM; j0 += 64) {
#pragma unroll
        for (int l = 0; l < 4; ++l) {
            int idx = t + l * 256;
            int jj = idx >> 4;
            int dq = (idx & 15) * 4;
            const float4 v4 = *(const float4*)(
                k + (((size_t)b * SDIM + j0 + jj) * HDIM) + n * DHEAD + dq);
            ks[jj][dq + 0] = v4.x;
            ks[jj][dq + 1] = v4.y;
            ks[jj][dq + 2] = v4.z;
            ks[jj][dq + 3] = v4.w;
        }
        __syncthreads();

        float s[8];
#pragma unroll
        for (int r = 0; r < 8; ++r) s[r] = 0.0f;
#pragma unroll 8
        for (int d = 0; d < 64; ++d) {
            float kv = ks[c][d];
#pragma unroll
            for (int r = 0; r < 8; ++r)
                s[r] = fmaf(qs[rg * 8 + r][d], kv, s[r]);
        }
        float add = (1.0f - (float)mask[b * SDIM + j0 + c]) * -10000.0f;
#pragma unroll
        for (int r = 0; r < 8; ++r) {
            int row = r0 + rg * 8 + r;
            scores[((size_t)n * SDIM + row) * SDIM + j0 + c] = s[r] * 0.125f + add;
        }
        __syncthreads();
    }
}

__global__ __launch_bounds__(256) void softmax_kernel(float* __restrict__ scores)
{
    float* p = scores + (size_t)blockIdx.x * SDIM;
    const int t = threadIdx.x;
    __shared__ float red[4];

    float a0 = p[t], a1 = p[t + 256];
    float m = fmaxf(a0, a1);
#pragma unroll
    for (int off = 32; off > 0; off >>= 1) m = fmaxf(m, __shfl_down(m, off, 64));
    if ((t & 63) == 0) red[t >> 6] = m;
    __syncthreads();
    m = fmaxf(fmaxf(red[0], red[1]), fmaxf(red[2], red[3]));

    float e0 = __expf(a0 - m), e1 = __expf(a1 - m);
    float s = e0 + e1;
#pragma unroll
    for (int off = 32; off > 0; off >>= 1) s += __shfl_down(s, off, 64);
    __syncthreads();
    if ((t & 63) == 0) red[t >> 6] = s;
    __syncthreads();
    s = red[0] + red[1] + red[2] + red[3];

    float inv = 1.0f / s;
    p[t] = e0 * inv;
    p[t + 256] = e1 * inv;
}

// PV: ctx (bf16) = prob @ v. grid (NH, S/32).
__global__ __launch_bounds__(256) void pv_kernel(
    const float* __restrict__ prob, const float* __restrict__ v,
    unsigned short* __restrict__ ctx, int b)
{
    const int n = blockIdx.x;
    const int r0 = blockIdx.y * 32;
    const int t = threadIdx.x;

    __shared__ float vs[64][64];
    __shared__ float ps[32][64];

    const int d = t & 63;
    const int rg = t >> 6;

    float acc[8];
#pragma unroll
    for (int r = 0; r < 8; ++r) acc[r] = 0.0f;

    for (int j0 = 0; j0 < SDIM; j0 += 64) {
#pragma unroll
        for (int l = 0; l < 4; ++l) {
            int idx = t + l * 256;
            int jj = idx >> 4;
            int dq = (idx & 15) * 4;
            *(float4*)&vs[jj][dq] = *(const float4*)(
                v + (((size_t)b * SDIM + j0 + jj) * HDIM) + n * DHEAD + dq);
        }
#pragma unroll
        for (int l = 0; l < 2; ++l) {
            int idx = t + l * 256;
            int r = idx >> 4;
            int jq = (idx & 15) * 4;
            *(float4*)&ps[r][jq] = *(const float4*)(
                prob + ((size_t)n * SDIM + r0 + r) * SDIM + j0 + jq);
        }
        __syncthreads();
#pragma unroll 8
        for (int jj = 0; jj < 64; ++jj) {
            float vv = vs[jj][d];
#pragma unroll
            for (int r = 0; r < 8; ++r)
                acc[r] = fmaf(ps[rg * 8 + r][jj], vv, acc[r]);
        }
        __syncthreads();
    }
#pragma unroll
    for (int r = 0; r < 8; ++r) {
        int row = r0 + rg * 8 + r;
        ctx[(((size_t)b * SDIM + row) * HDIM) + n * DHEAD + d] = f2bf(acc[r]);
    }
}

// ---------------------------------------------------------------------------
// Fused residual + LayerNorm: out = LN(x(f32) + resid(bf16)) * g + b
// OUTF32: write fp32 (final output), else bf16.
// ---------------------------------------------------------------------------
template<bool OUTF32>
__global__ __launch_bounds__(256) void ln_kernel(
    const float* __restrict__ x, const unsigned short* __restrict__ resid,
    const float* __restrict__ ln, void* __restrict__ out)
{
    const int row = blockIdx.x;
    const float* xr = x + (size_t)row * HDIM;
    const unsigned short* rr = resid + (size_t)row * HDIM;
    const int t = threadIdx.x;
    __shared__ float red[4];

    float z[4];
    float s = 0.0f;
#pragma unroll
    for (int i = 0; i < 4; ++i) {
        int c = t + i * 256;
        z[i] = xr[c] + bf2f(rr[c]);
        s += z[i];
    }
#pragma unroll
    for (int off = 32; off > 0; off >>= 1) s += __shfl_down(s, off, 64);
    if ((t & 63) == 0) red[t >> 6] = s;
    __syncthreads();
    s = red[0] + red[1] + red[2] + red[3];
    float mean = s * (1.0f / (float)HDIM);

    float vs = 0.0f;
#pragma unroll
    for (int i = 0; i < 4; ++i) {
        float d = z[i] - mean;
        vs += d * d;
    }
#pragma unroll
    for (int off = 32; off > 0; off >>= 1) vs += __shfl_down(vs, off, 64);
    __syncthreads();
    if ((t & 63) == 0) red[t >> 6] = vs;
    __syncthreads();
    vs = red[0] + red[1] + red[2] + red[3];
    float inv = rsqrtf(vs * (1.0f / (float)HDIM) + 1e-12f);

#pragma unroll
    for (int i = 0; i < 4; ++i) {
        int c = t + i * 256;
        float o = (z[i] - mean) * inv * ln[c] + ln[HDIM + c];
        if (OUTF32)
            ((float*)out)[(size_t)row * HDIM + c] = o;
        else
            ((unsigned short*)out)[(size_t)row * HDIM + c] = f2bf(o);
    }
}

// fp32 -> bf16 elementwise (vectorized x4)
__global__ __launch_bounds__(256) void cvt_bf16_kernel(
    const float* __restrict__ in, unsigned short* __restrict__ out, int n4)
{
    int i = blockIdx.x * 256 + threadIdx.x;
    if (i < n4) {
        float4 v = ((const float4*)in)[i];
        ushort4 o;
        o.x = f2bf(v.x); o.y = f2bf(v.y); o.z = f2bf(v.z); o.w = f2bf(v.w);
        ((ushort4*)out)[i] = o;
    }
}

// ---------------------------------------------------------------------------
extern "C" void kernel_launch(void* const* d_in, const int* in_sizes, int n_in,
                              void* d_out, int out_size, void* d_ws, size_t ws_size,
                              hipStream_t stream)
{
    const float* in_hidden = (const float*)d_in[0];
    const float* enc_f     = (const float*)d_in[1];
    const int* attn_mask   = (const int*)d_in[2];
    const int* enc_attn_mask = (const int*)d_in[3];
    const float* sa_qkv_w  = (const float*)d_in[4];
    const float* sa_qkv_b  = (const float*)d_in[5];
    const float* sa_out_w  = (const float*)d_in[6];
    const float* sa_out_b  = (const float*)d_in[7];
    const float* sa_ln     = (const float*)d_in[8];
    const float* ca_qkv_w  = (const float*)d_in[9];
    const float* ca_qkv_b  = (const float*)d_in[10];
    const float* ca_out_w  = (const float*)d_in[11];
    const float* ca_out_b  = (const float*)d_in[12];
    const float* ca_ln     = (const float*)d_in[13];
    const float* o1_w      = (const float*)d_in[14];
    const float* o1_b      = (const float*)d_in[15];
    const float* o1_ln     = (const float*)d_in[16];
    const float* ffn_w     = (const float*)d_in[17];
    const float* ffn_b     = (const float*)d_in[18];
    const float* o2_w      = (const float*)d_in[19];
    const float* o2_b      = (const float*)d_in[20];
    const float* o2_ln     = (const float*)d_in[21];

    const size_t MH  = (size_t)MROWS * HDIM;   // 2,097,152
    const size_t Hsq = (size_t)HDIM * HDIM;    // 1,048,576
    const size_t HF  = (size_t)HDIM * FDIM;    // 4,194,304

    char* p = (char*)d_ws;
    unsigned short* wbf = (unsigned short*)p; p += (9 * Hsq + 2 * HF) * 2;  // 34 MiB
    float* qb     = (float*)p; p += MH * 4;                                  // 8 MiB
    float* kb     = (float*)p; p += MH * 4;
    float* vb     = (float*)p; p += MH * 4;
    float* t2     = (float*)p; p += MH * 4;
    float* scores = (float*)p; p += (size_t)NHEAD * SDIM * SDIM * 4;         // 16 MiB
    unsigned short* tmp8b  = (unsigned short*)p; p += (size_t)MROWS * FDIM * 2; // 16 MiB
    unsigned short* h      = (unsigned short*)p; p += MH * 2;                // 4 MiB each
    unsigned short* enc_bf = (unsigned short*)p; p += MH * 2;
    unsigned short* ctx    = (unsigned short*)p; p += MH * 2;
    unsigned short* attn1  = (unsigned short*)p; p += MH * 2;
    unsigned short* crossb = (unsigned short*)p; p += MH * 2;
    unsigned short* attn2  = (unsigned short*)p; p += MH * 2;

    // per-layer transposed bf16 weight slots
    unsigned short* w_saqkv = wbf;                 // 3 x [H][H]
    unsigned short* w_saout = wbf + 3 * Hsq;
    unsigned short* w_caqkv = wbf + 4 * Hsq;
    unsigned short* w_caout = wbf + 7 * Hsq;
    unsigned short* w_o1    = wbf + 8 * Hsq;
    unsigned short* w_ffn   = wbf + 9 * Hsq;       // [F][H]
    unsigned short* w_o2    = wbf + 9 * Hsq + HF;  // [H][F]

    cvt_bf16_kernel<<<(MH / 4 + 255) / 256, 256, 0, stream>>>(in_hidden, h, MH / 4);
    cvt_bf16_kernel<<<(MH / 4 + 255) / 256, 256, 0, stream>>>(enc_f, enc_bf, MH / 4);

    for (int l = 0; l < LNUM; ++l) {
        // ---- weight convert+transpose for this layer ----
        convtrans_kernel<<<dim3(HDIM / 64, HDIM / 64, 3), 256, 0, stream>>>(
            sa_qkv_w + (size_t)l * 3 * Hsq, w_saqkv, HDIM, HDIM);
        convtrans_kernel<<<dim3(HDIM / 64, HDIM / 64, 1), 256, 0, stream>>>(
            sa_out_w + (size_t)l * Hsq, w_saout, HDIM, HDIM);
        convtrans_kernel<<<dim3(HDIM / 64, HDIM / 64, 3), 256, 0, stream>>>(
            ca_qkv_w + (size_t)l * 3 * Hsq, w_caqkv, HDIM, HDIM);
        convtrans_kernel<<<dim3(HDIM / 64, HDIM / 64, 1), 256, 0, stream>>>(
            ca_out_w + (size_t)l * Hsq, w_caout, HDIM, HDIM);
        convtrans_kernel<<<dim3(HDIM / 64, HDIM / 64, 1), 256, 0, stream>>>(
            o1_w + (size_t)l * Hsq, w_o1, HDIM, HDIM);
        convtrans_kernel<<<dim3(FDIM / 64, HDIM / 64, 1), 256, 0, stream>>>(
            ffn_w + (size_t)l * HF, w_ffn, HDIM, FDIM);
        convtrans_kernel<<<dim3(HDIM / 64, FDIM / 64, 1), 256, 0, stream>>>(
            o2_w + (size_t)l * HF, w_o2, FDIM, HDIM);

        // ---- self attention ----
        mfma_gemm<64, false, false><<<dim3(MROWS / 128, HDIM / 64), 256, 0, stream>>>(
            h, w_saqkv + 0 * Hsq, sa_qkv_b + ((size_t)l * 3 + 0) * HDIM, qb, MROWS, HDIM, HDIM);
        mfma_gemm<64, false, false><<<dim3(MROWS / 128, HDIM / 64), 256, 0, stream>>>(
            h, w_saqkv + 1 * Hsq, sa_qkv_b + ((size_t)l * 3 + 1) * HDIM, kb, MROWS, HDIM, HDIM);
        mfma_gemm<64, false, false><<<dim3(MROWS / 128, HDIM / 64), 256, 0, stream>>>(
            h, w_saqkv + 2 * Hsq, sa_qkv_b + ((size_t)l * 3 + 2) * HDIM, vb, MROWS, HDIM, HDIM);
        for (int b = 0; b < BDIM; ++b) {
            qk_kernel<<<dim3(NHEAD, SDIM / 32), 256, 0, stream>>>(qb, kb, attn_mask, scores, b);
            softmax_kernel<<<NHEAD * SDIM, 256, 0, stream>>>(scores);
            pv_kernel<<<dim3(NHEAD, SDIM / 32), 256, 0, stream>>>(scores, vb, ctx, b);
        }
        mfma_gemm<64, false, false><<<dim3(MROWS / 128, HDIM / 64), 256, 0, stream>>>(
            ctx, w_saout, sa_out_b + (size_t)l * HDIM, t2, MROWS, HDIM, HDIM);
        ln_kernel<false><<<MROWS, 256, 0, stream>>>(t2, h, sa_ln + (size_t)l * 2 * HDIM, attn1);

        // ---- cross attention (residual = h) ----
        mfma_gemm<64, false, false><<<dim3(MROWS / 128, HDIM / 64), 256, 0, stream>>>(
            h, w_caqkv + 0 * Hsq, ca_qkv_b + ((size_t)l * 3 + 0) * HDIM, qb, MROWS, HDIM, HDIM);
        mfma_gemm<64, false, false><<<dim3(MROWS / 128, HDIM / 64), 256, 0, stream>>>(
            enc_bf, w_caqkv + 1 * Hsq, ca_qkv_b + ((size_t)l * 3 + 1) * HDIM, kb, MROWS, HDIM, HDIM);
        mfma_gemm<64, false, false><<<dim3(MROWS / 128, HDIM / 64), 256, 0, stream>>>(
            enc_bf, w_caqkv + 2 * Hsq, ca_qkv_b + ((size_t)l * 3 + 2) * HDIM, vb, MROWS, HDIM, HDIM);
        for (int b = 0; b < BDIM; ++b) {
            qk_kernel<<<dim3(NHEAD, SDIM / 32), 256, 0, stream>>>(qb, kb, enc_attn_mask, scores, b);
            softmax_kernel<<<NHEAD * SDIM, 256, 0, stream>>>(scores);
            pv_kernel<<<dim3(NHEAD, SDIM / 32), 256, 0, stream>>>(scores, vb, ctx, b);
        }
        mfma_gemm<64, false, false><<<dim3(MROWS / 128, HDIM / 64), 256, 0, stream>>>(
            ctx, w_caout, ca_out_b + (size_t)l * HDIM, t2, MROWS, HDIM, HDIM);
        ln_kernel<false><<<MROWS, 256, 0, stream>>>(t2, h, ca_ln + (size_t)l * 2 * HDIM, crossb);

        // ---- output_1 ----
        mfma_gemm<64, false, false><<<dim3(MROWS / 128, HDIM / 64), 256, 0, stream>>>(
            attn1, w_o1, o1_b + (size_t)l * HDIM, t2, MROWS, HDIM, HDIM);
        ln_kernel<false><<<MROWS, 256, 0, stream>>>(t2, crossb, o1_ln + (size_t)l * 2 * HDIM, attn2);

        // ---- FFN: gelu fused into epilogue, bf16 out ----
        mfma_gemm<128, true, true><<<dim3(MROWS / 128, FDIM / 128), 256, 0, stream>>>(
            attn2, w_ffn, ffn_b + (size_t)l * FDIM, tmp8b, MROWS, FDIM, HDIM);
        mfma_gemm<64, false, false><<<dim3(MROWS / 128, HDIM / 64), 256, 0, stream>>>(
            tmp8b, w_o2, o2_b + (size_t)l * HDIM, t2, MROWS, HDIM, FDIM);
        if (l == LNUM - 1)
            ln_kernel<true><<<MROWS, 256, 0, stream>>>(
                t2, attn2, o2_ln + (size_t)l * 2 * HDIM, (float*)d_out);
        else
            ln_kernel<false><<<MROWS, 256, 0, stream>>>(
                t2, attn2, o2_ln + (size_t)l * 2 * HDIM, h);
    }
}

// Round 4
// 2425.502 us; speedup vs baseline: 5.4883x; 2.4312x over previous
//
#include <hip/hip_runtime.h>

// ---------------------------------------------------------------------------
// T5 backbone forward, round 3:
//  - fused QKV projection GEMM (N=3072, grid 768 blocks, bf16 out)
//  - flash-style MFMA attention (QK^T + online softmax + PV, one kernel)
//  - bf16 MFMA GEMMs elsewhere (m97 structure), gelu fused in FFN epilogue
//  - fused residual+LN
// ---------------------------------------------------------------------------

#define LNUM 6
#define HDIM 1024
#define NHEAD 16
#define DHEAD 64
#define BDIM 4
#define SDIM 512
#define FDIM 4096
#define MROWS (BDIM * SDIM)   // 2048

typedef __bf16 bf16_t;
typedef bf16_t bf16x8 __attribute__((ext_vector_type(8)));
typedef float f32x4 __attribute__((ext_vector_type(4)));

__device__ __forceinline__ float bf2f(unsigned short u) {
    union { unsigned int i; float f; } x;
    x.i = ((unsigned int)u) << 16;
    return x.f;
}

__device__ __forceinline__ unsigned short f2bf(float f) {
    union { float f; unsigned int i; } u;
    u.f = f;
    unsigned int x = u.i;
    unsigned int lsb = (x >> 16) & 1u;
    x += 0x7fffu + lsb;           // round-to-nearest-even
    return (unsigned short)(x >> 16);
}

// async global->LDS, 16 bytes per lane; lds dest = wave-uniform base + lane*16
__device__ __forceinline__ void async16(const unsigned short* g, unsigned short* l) {
    __builtin_amdgcn_global_load_lds(
        (const __attribute__((address_space(1))) unsigned int*)g,
        (__attribute__((address_space(3))) unsigned int*)l, 16, 0, 0);
}

// ---------------------------------------------------------------------------
// MFMA GEMM: C[M,N] = A[M,K](bf16) @ BT[N,K](bf16)^T + bias(f32)
// BM=128, BK=64, 256 threads (4 waves as 2x2), per-wave 64 x BN/2 output.
// ---------------------------------------------------------------------------
template<int BN, bool GELU, bool OUTBF16>
__global__ __launch_bounds__(256) void mfma_gemm(
    const unsigned short* __restrict__ A,
    const unsigned short* __restrict__ BT,
    const float* __restrict__ bias,
    void* __restrict__ Cv,
    int M, int N, int K)
{
    constexpr int BM = 128;
    constexpr int BK = 64;
    constexpr int MI = 4;
    constexpr int NJ = BN / 32;

    __shared__ unsigned short As[BM][BK];
    __shared__ unsigned short Bs[BN][BK];

    const int t = threadIdx.x;
    const int w = t >> 6;
    const int lane = t & 63;
    const int quad = lane >> 4;
    const int cm = lane & 15;
    const int wrow = (w >> 1) * 64;
    const int wcol = (w & 1) * (BN / 2);
    const int row0 = blockIdx.x * BM;
    const int col0 = blockIdx.y * BN;

    f32x4 acc[MI][NJ] = {};

    const int lrow = lane >> 3;
    const int lcol = (lane & 7) * 8;

    for (int k0 = 0; k0 < K; k0 += BK) {
#pragma unroll
        for (int j = 0; j < 4; ++j) {
            int mb = w * 32 + j * 8;
            async16(A + (size_t)(row0 + mb + lrow) * K + k0 + lcol, &As[mb][0]);
        }
#pragma unroll
        for (int j = 0; j < NJ; ++j) {
            int nb = w * (BN / 4) + j * 8;
            async16(BT + (size_t)(col0 + nb + lrow) * K + k0 + lcol, &Bs[nb][0]);
        }
        __syncthreads();

#pragma unroll
        for (int kk = 0; kk < BK; kk += 32) {
            bf16x8 av[MI], bv[NJ];
#pragma unroll
            for (int i = 0; i < MI; ++i)
                av[i] = *(const bf16x8*)&As[wrow + 16 * i + cm][kk + quad * 8];
#pragma unroll
            for (int j = 0; j < NJ; ++j)
                bv[j] = *(const bf16x8*)&Bs[wcol + 16 * j + cm][kk + quad * 8];
#pragma unroll
            for (int i = 0; i < MI; ++i)
#pragma unroll
                for (int j = 0; j < NJ; ++j)
                    acc[i][j] = __builtin_amdgcn_mfma_f32_16x16x32_bf16(
                        av[i], bv[j], acc[i][j], 0, 0, 0);
        }
        __syncthreads();
    }

#pragma unroll
    for (int j = 0; j < NJ; ++j) {
        int col = col0 + wcol + 16 * j + cm;
        float bb = bias[col];
#pragma unroll
        for (int i = 0; i < MI; ++i) {
#pragma unroll
            for (int r = 0; r < 4; ++r) {
                int row = row0 + wrow + 16 * i + quad * 4 + r;
                float c = acc[i][j][r] + bb;
                if (GELU) {
                    float u = 0.7978845608028654f * (c + 0.044715f * c * c * c);
                    c = 0.5f * c * (1.0f + tanhf(u));
                }
                if (OUTBF16)
                    ((unsigned short*)Cv)[(size_t)row * N + col] = f2bf(c);
                else
                    ((float*)Cv)[(size_t)row * N + col] = c;
            }
        }
    }
}

// ---------------------------------------------------------------------------
// Fused QKV GEMM: A[M,K] @ BT[3072,K]^T + bias[3072] -> q/k/v bf16 [M][1024]
// Same structure, BN=64; column block selects destination matrix.
// ---------------------------------------------------------------------------
__global__ __launch_bounds__(256) void mfma_gemm_qkv(
    const unsigned short* __restrict__ A,
    const unsigned short* __restrict__ BT,
    const float* __restrict__ bias,
    unsigned short* __restrict__ qo,
    unsigned short* __restrict__ ko,
    unsigned short* __restrict__ vo,
    int M, int K)
{
    constexpr int BM = 128;
    constexpr int BK = 64;
    constexpr int BN = 64;
    constexpr int MI = 4;
    constexpr int NJ = 2;

    __shared__ unsigned short As[BM][BK];
    __shared__ unsigned short Bs[BN][BK];

    const int t = threadIdx.x;
    const int w = t >> 6;
    const int lane = t & 63;
    const int quad = lane >> 4;
    const int cm = lane & 15;
    const int wrow = (w >> 1) * 64;
    const int wcol = (w & 1) * 32;
    const int row0 = blockIdx.x * BM;
    const int col0 = blockIdx.y * BN;      // 0..3071

    f32x4 acc[MI][NJ] = {};

    const int lrow = lane >> 3;
    const int lcol = (lane & 7) * 8;

    for (int k0 = 0; k0 < K; k0 += BK) {
#pragma unroll
        for (int j = 0; j < 4; ++j) {
            int mb = w * 32 + j * 8;
            async16(A + (size_t)(row0 + mb + lrow) * K + k0 + lcol, &As[mb][0]);
        }
#pragma unroll
        for (int j = 0; j < NJ; ++j) {
            int nb = w * 16 + j * 8;
            async16(BT + (size_t)(col0 + nb + lrow) * K + k0 + lcol, &Bs[nb][0]);
        }
        __syncthreads();

#pragma unroll
        for (int kk = 0; kk < BK; kk += 32) {
            bf16x8 av[MI], bv[NJ];
#pragma unroll
            for (int i = 0; i < MI; ++i)
                av[i] = *(const bf16x8*)&As[wrow + 16 * i + cm][kk + quad * 8];
#pragma unroll
            for (int j = 0; j < NJ; ++j)
                bv[j] = *(const bf16x8*)&Bs[wcol + 16 * j + cm][kk + quad * 8];
#pragma unroll
            for (int i = 0; i < MI; ++i)
#pragma unroll
                for (int j = 0; j < NJ; ++j)
                    acc[i][j] = __builtin_amdgcn_mfma_f32_16x16x32_bf16(
                        av[i], bv[j], acc[i][j], 0, 0, 0);
        }
        __syncthreads();
    }

    const int which = col0 >> 10;
    unsigned short* dst = (which == 0) ? qo : (which == 1) ? ko : vo;
    const int cbase = col0 & 1023;

#pragma unroll
    for (int j = 0; j < NJ; ++j) {
        int col = col0 + wcol + 16 * j + cm;
        float bb = bias[col];
        int coll = cbase + wcol + 16 * j + cm;
#pragma unroll
        for (int i = 0; i < MI; ++i) {
#pragma unroll
            for (int r = 0; r < 4; ++r) {
                int row = row0 + wrow + 16 * i + quad * 4 + r;
                dst[(size_t)row * HDIM + coll] = f2bf(acc[i][j][r] + bb);
            }
        }
    }
}

// ---------------------------------------------------------------------------
// Flash attention: grid (S/64, NH, B), 256 threads (4 waves).
// Each wave owns 16 q-rows; KV tiles of 64; online softmax; ctx bf16 out.
// q,k,v: bf16 [B*S][H]; mask: int [B][S].
// ---------------------------------------------------------------------------
__global__ __launch_bounds__(256) void flash_attn(
    const unsigned short* __restrict__ q,
    const unsigned short* __restrict__ k,
    const unsigned short* __restrict__ v,
    const int* __restrict__ mask,
    unsigned short* __restrict__ ctx)
{
    __shared__ unsigned short Qs[64][64];
    __shared__ unsigned short Ks[64][64];
    __shared__ unsigned short Vs[64][72];      // transposed: Vs[d][j]
    __shared__ unsigned short Ps[4][16][72];   // per-wave P tile [m][j]

    const int t = threadIdx.x;
    const int w = t >> 6;
    const int lane = t & 63;
    const int quad = lane >> 4;
    const int cm = lane & 15;

    const int q0 = blockIdx.x * 64;
    const int h = blockIdx.y;
    const int b = blockIdx.z;
    const size_t rowbase = (size_t)b * SDIM;
    const int hoff = h * DHEAD;

    // stage Q tile (64x64)
#pragma unroll
    for (int l = 0; l < 2; ++l) {
        int idx = t + l * 256;           // 0..511
        int r = idx >> 3;                // 0..63
        int c = (idx & 7) * 8;
        *(uint4*)&Qs[r][c] = *(const uint4*)(q + (rowbase + q0 + r) * HDIM + hoff + c);
    }

    float m_prev[4] = {-1e30f, -1e30f, -1e30f, -1e30f};
    float l_sum[4] = {0.0f, 0.0f, 0.0f, 0.0f};
    f32x4 oacc[4] = {};

    for (int j0 = 0; j0 < SDIM; j0 += 64) {
        __syncthreads();   // previous iteration's compute done before restaging
        // stage K tile (64x64) and V tile transposed
#pragma unroll
        for (int l = 0; l < 2; ++l) {
            int idx = t + l * 256;
            int r = idx >> 3;
            int c = (idx & 7) * 8;
            *(uint4*)&Ks[r][c] = *(const uint4*)(k + (rowbase + j0 + r) * HDIM + hoff + c);
        }
#pragma unroll
        for (int l = 0; l < 4; ++l) {
            int idx = t + l * 256;       // 0..1023
            int jj = idx >> 4;           // 0..63
            int d0 = (idx & 15) * 4;
            ushort4 vv = *(const ushort4*)(v + (rowbase + j0 + jj) * HDIM + hoff + d0);
            Vs[d0 + 0][jj] = vv.x;
            Vs[d0 + 1][jj] = vv.y;
            Vs[d0 + 2][jj] = vv.z;
            Vs[d0 + 3][jj] = vv.w;
        }
        __syncthreads();

        // S = Q K^T for this wave's 16 rows x 64 kv cols
        f32x4 sacc[4] = {};
#pragma unroll
        for (int kk = 0; kk < 64; kk += 32) {
            bf16x8 av = *(const bf16x8*)&Qs[w * 16 + cm][kk + quad * 8];
#pragma unroll
            for (int j2 = 0; j2 < 4; ++j2) {
                bf16x8 bv = *(const bf16x8*)&Ks[j2 * 16 + cm][kk + quad * 8];
                sacc[j2] = __builtin_amdgcn_mfma_f32_16x16x32_bf16(av, bv, sacc[j2], 0, 0, 0);
            }
        }

        // mask adders for this lane's 4 columns
        float madd[4];
#pragma unroll
        for (int j2 = 0; j2 < 4; ++j2)
            madd[j2] = (1.0f - (float)mask[b * SDIM + j0 + j2 * 16 + cm]) * -10000.0f;

        // online softmax per row r (rows quad*4+r of the wave's 16)
#pragma unroll
        for (int r = 0; r < 4; ++r) {
            float s0 = sacc[0][r] * 0.125f + madd[0];
            float s1 = sacc[1][r] * 0.125f + madd[1];
            float s2 = sacc[2][r] * 0.125f + madd[2];
            float s3 = sacc[3][r] * 0.125f + madd[3];
            float rm = fmaxf(fmaxf(s0, s1), fmaxf(s2, s3));
#pragma unroll
            for (int mo = 1; mo < 16; mo <<= 1)
                rm = fmaxf(rm, __shfl_xor(rm, mo, 64));
            float new_m = fmaxf(m_prev[r], rm);
            float alpha = __expf(m_prev[r] - new_m);
            m_prev[r] = new_m;
            float p0 = __expf(s0 - new_m);
            float p1 = __expf(s1 - new_m);
            float p2 = __expf(s2 - new_m);
            float p3 = __expf(s3 - new_m);
            float rs = p0 + p1 + p2 + p3;
#pragma unroll
            for (int mo = 1; mo < 16; mo <<= 1)
                rs += __shfl_xor(rs, mo, 64);
            l_sum[r] = l_sum[r] * alpha + rs;
#pragma unroll
            for (int d2 = 0; d2 < 4; ++d2)
                oacc[d2][r] *= alpha;
            int prow = quad * 4 + r;
            Ps[w][prow][0 * 16 + cm] = f2bf(p0);
            Ps[w][prow][1 * 16 + cm] = f2bf(p1);
            Ps[w][prow][2 * 16 + cm] = f2bf(p2);
            Ps[w][prow][3 * 16 + cm] = f2bf(p3);
        }
        // wave-synchronous: own wave's Ps writes visible after lgkmcnt (compiler)

        // O += P V
#pragma unroll
        for (int kk = 0; kk < 64; kk += 32) {
            bf16x8 pa = *(const bf16x8*)&Ps[w][cm][kk + quad * 8];
#pragma unroll
            for (int d2 = 0; d2 < 4; ++d2) {
                bf16x8 bv = *(const bf16x8*)&Vs[d2 * 16 + cm][kk + quad * 8];
                oacc[d2] = __builtin_amdgcn_mfma_f32_16x16x32_bf16(pa, bv, oacc[d2], 0, 0, 0);
            }
        }
    }

    // epilogue: divide by l, write ctx
#pragma unroll
    for (int r = 0; r < 4; ++r) {
        float inv = 1.0f / l_sum[r];
        int row = q0 + w * 16 + quad * 4 + r;
#pragma unroll
        for (int d2 = 0; d2 < 4; ++d2) {
            ctx[(rowbase + row) * HDIM + hoff + d2 * 16 + cm] = f2bf(oacc[d2][r] * inv);
        }
    }
}

// ---------------------------------------------------------------------------
// Weight convert + transpose: fp32 [K][N] -> bf16 [N][K]. 64x64 tiles.
// ---------------------------------------------------------------------------
__global__ __launch_bounds__(256) void convtrans_kernel(
    const float* __restrict__ in, unsigned short* __restrict__ out, int K, int N)
{
    __shared__ unsigned short tile[64][72];
    const size_t moff = (size_t)blockIdx.z * K * N;
    const int n0 = blockIdx.x * 64, k0 = blockIdx.y * 64;
    const int t = threadIdx.x;
#pragma unroll
    for (int l = 0; l < 4; ++l) {
        int idx = t + l * 256;
        int kk = idx >> 4;
        int nn = (idx & 15) * 4;
        float4 v = *(const float4*)(in + moff + (size_t)(k0 + kk) * N + n0 + nn);
        tile[nn + 0][kk] = f2bf(v.x);
        tile[nn + 1][kk] = f2bf(v.y);
        tile[nn + 2][kk] = f2bf(v.z);
        tile[nn + 3][kk] = f2bf(v.w);
    }
    __syncthreads();
#pragma unroll
    for (int l = 0; l < 2; ++l) {
        int c = t + l * 256;
        int nn = c >> 3;
        int kk = (c & 7) * 8;
        *(uint4*)(out + moff + (size_t)(n0 + nn) * K + k0 + kk) =
            *(const uint4*)&tile[nn][kk];
    }
}

// ---------------------------------------------------------------------------
// Fused residual + LayerNorm: out = LN(x(f32) + resid(bf16)) * g + b
// ---------------------------------------------------------------------------
template<bool OUTF32>
__global__ __launch_bounds__(256) void ln_kernel(
    const float* __restrict__ x, const unsigned short* __restrict__ resid,
    const float* __restrict__ ln, void* __restrict__ out)
{
    const int row = blockIdx.x;
    const float* xr = x + (size_t)row * HDIM;
    const unsigned short* rr = resid + (size_t)row * HDIM;
    const int t = threadIdx.x;
    __shared__ float red[4];

    float z[4];
    float s = 0.0f;
#pragma unroll
    for (int i = 0; i < 4; ++i) {
        int c = t + i * 256;
        z[i] = xr[c] + bf2f(rr[c]);
        s += z[i];
    }
#pragma unroll
    for (int off = 32; off > 0; off >>= 1) s += __shfl_down(s, off, 64);
    if ((t & 63) == 0) red[t >> 6] = s;
    __syncthreads();
    s = red[0] + red[1] + red[2] + red[3];
    float mean = s * (1.0f / (float)HDIM);

    float vs = 0.0f;
#pragma unroll
    for (int i = 0; i < 4; ++i) {
        float d = z[i] - mean;
        vs += d * d;
    }
#pragma unroll
    for (int off = 32; off > 0; off >>= 1) vs += __shfl_down(vs, off, 64);
    __syncthreads();
    if ((t & 63) == 0) red[t >> 6] = vs;
    __syncthreads();
    vs = red[0] + red[1] + red[2] + red[3];
    float inv = rsqrtf(vs * (1.0f / (float)HDIM) + 1e-12f);

#pragma unroll
    for (int i = 0; i < 4; ++i) {
        int c = t + i * 256;
        float o = (z[i] - mean) * inv * ln[c] + ln[HDIM + c];
        if (OUTF32)
            ((float*)out)[(size_t)row * HDIM + c] = o;
        else
            ((unsigned short*)out)[(size_t)row * HDIM + c] = f2bf(o);
    }
}

__global__ __launch_bounds__(256) void cvt_bf16_kernel(
    const float* __restrict__ in, unsigned short* __restrict__ out, int n4)
{
    int i = blockIdx.x * 256 + threadIdx.x;
    if (i < n4) {
        float4 v = ((const float4*)in)[i];
        ushort4 o;
        o.x = f2bf(v.x); o.y = f2bf(v.y); o.z = f2bf(v.z); o.w = f2bf(v.w);
        ((ushort4*)out)[i] = o;
    }
}

// ---------------------------------------------------------------------------
extern "C" void kernel_launch(void* const* d_in, const int* in_sizes, int n_in,
                              void* d_out, int out_size, void* d_ws, size_t ws_size,
                              hipStream_t stream)
{
    const float* in_hidden = (const float*)d_in[0];
    const float* enc_f     = (const float*)d_in[1];
    const int* attn_mask   = (const int*)d_in[2];
    const int* enc_attn_mask = (const int*)d_in[3];
    const float* sa_qkv_w  = (const float*)d_in[4];
    const float* sa_qkv_b  = (const float*)d_in[5];
    const float* sa_out_w  = (const float*)d_in[6];
    const float* sa_out_b  = (const float*)d_in[7];
    const float* sa_ln     = (const float*)d_in[8];
    const float* ca_qkv_w  = (const float*)d_in[9];
    const float* ca_qkv_b  = (const float*)d_in[10];
    const float* ca_out_w  = (const float*)d_in[11];
    const float* ca_out_b  = (const float*)d_in[12];
    const float* ca_ln     = (const float*)d_in[13];
    const float* o1_w      = (const float*)d_in[14];
    const float* o1_b      = (const float*)d_in[15];
    const float* o1_ln     = (const float*)d_in[16];
    const float* ffn_w     = (const float*)d_in[17];
    const float* ffn_b     = (const float*)d_in[18];
    const float* o2_w      = (const float*)d_in[19];
    const float* o2_b      = (const float*)d_in[20];
    const float* o2_ln     = (const float*)d_in[21];

    const size_t MH  = (size_t)MROWS * HDIM;   // 2,097,152
    const size_t Hsq = (size_t)HDIM * HDIM;    // 1,048,576
    const size_t HF  = (size_t)HDIM * FDIM;    // 4,194,304

    char* p = (char*)d_ws;
    unsigned short* wbf = (unsigned short*)p; p += (9 * Hsq + 2 * HF) * 2;  // ~34 MiB
    float* t2     = (float*)p; p += MH * 4;                                  // 8 MiB
    unsigned short* qb     = (unsigned short*)p; p += MH * 2;                // 4 MiB each
    unsigned short* kb     = (unsigned short*)p; p += MH * 2;
    unsigned short* vb     = (unsigned short*)p; p += MH * 2;
    unsigned short* ctx    = (unsigned short*)p; p += MH * 2;
    unsigned short* h      = (unsigned short*)p; p += MH * 2;
    unsigned short* enc_bf = (unsigned short*)p; p += MH * 2;
    unsigned short* attn1  = (unsigned short*)p; p += MH * 2;
    unsigned short* crossb = (unsigned short*)p; p += MH * 2;
    unsigned short* attn2  = (unsigned short*)p; p += MH * 2;
    unsigned short* tmp8b  = (unsigned short*)p; p += (size_t)MROWS * FDIM * 2; // 16 MiB

    unsigned short* w_saqkv = wbf;                 // [3072][1024]
    unsigned short* w_saout = wbf + 3 * Hsq;
    unsigned short* w_caqkv = wbf + 4 * Hsq;       // [3072][1024]
    unsigned short* w_caout = wbf + 7 * Hsq;
    unsigned short* w_o1    = wbf + 8 * Hsq;
    unsigned short* w_ffn   = wbf + 9 * Hsq;       // [4096][1024]
    unsigned short* w_o2    = wbf + 9 * Hsq + HF;  // [1024][4096]

    cvt_bf16_kernel<<<(MH / 4 + 255) / 256, 256, 0, stream>>>(in_hidden, h, MH / 4);
    cvt_bf16_kernel<<<(MH / 4 + 255) / 256, 256, 0, stream>>>(enc_f, enc_bf, MH / 4);

    for (int l = 0; l < LNUM; ++l) {
        // ---- weight convert+transpose for this layer ----
        convtrans_kernel<<<dim3(HDIM / 64, HDIM / 64, 3), 256, 0, stream>>>(
            sa_qkv_w + (size_t)l * 3 * Hsq, w_saqkv, HDIM, HDIM);
        convtrans_kernel<<<dim3(HDIM / 64, HDIM / 64, 1), 256, 0, stream>>>(
            sa_out_w + (size_t)l * Hsq, w_saout, HDIM, HDIM);
        convtrans_kernel<<<dim3(HDIM / 64, HDIM / 64, 3), 256, 0, stream>>>(
            ca_qkv_w + (size_t)l * 3 * Hsq, w_caqkv, HDIM, HDIM);
        convtrans_kernel<<<dim3(HDIM / 64, HDIM / 64, 1), 256, 0, stream>>>(
            ca_out_w + (size_t)l * Hsq, w_caout, HDIM, HDIM);
        convtrans_kernel<<<dim3(HDIM / 64, HDIM / 64, 1), 256, 0, stream>>>(
            o1_w + (size_t)l * Hsq, w_o1, HDIM, HDIM);
        convtrans_kernel<<<dim3(FDIM / 64, HDIM / 64, 1), 256, 0, stream>>>(
            ffn_w + (size_t)l * HF, w_ffn, HDIM, FDIM);
        convtrans_kernel<<<dim3(HDIM / 64, FDIM / 64, 1), 256, 0, stream>>>(
            o2_w + (size_t)l * HF, w_o2, FDIM, HDIM);

        // ---- self attention ----
        mfma_gemm_qkv<<<dim3(MROWS / 128, 3072 / 64), 256, 0, stream>>>(
            h, w_saqkv, sa_qkv_b + (size_t)l * 3 * HDIM, qb, kb, vb, MROWS, HDIM);
        flash_attn<<<dim3(SDIM / 64, NHEAD, BDIM), 256, 0, stream>>>(
            qb, kb, vb, attn_mask, ctx);
        mfma_gemm<64, false, false><<<dim3(MROWS / 128, HDIM / 64), 256, 0, stream>>>(
            ctx, w_saout, sa_out_b + (size_t)l * HDIM, t2, MROWS, HDIM, HDIM);
        ln_kernel<false><<<MROWS, 256, 0, stream>>>(t2, h, sa_ln + (size_t)l * 2 * HDIM, attn1);

        // ---- cross attention (residual = h; KV from encoder states) ----
        mfma_gemm_qkv<<<dim3(MROWS / 128, 1024 / 64), 256, 0, stream>>>(
            h, w_caqkv, ca_qkv_b + (size_t)l * 3 * HDIM, qb, kb, vb, MROWS, HDIM);
        // K and V come from enc: launch the remaining 2/3 of columns with enc input
        mfma_gemm_qkv<<<dim3(MROWS / 128, 2048 / 64), 256, 0, stream>>>(
            enc_bf, w_caqkv + Hsq,                       // skip Q weights
            ca_qkv_b + (size_t)l * 3 * HDIM + HDIM,      // skip Q bias
            kb, vb, vb /* which: 0->kb, 1->vb */, MROWS, HDIM);
        flash_attn<<<dim3(SDIM / 64, NHEAD, BDIM), 256, 0, stream>>>(
            qb, kb, vb, enc_attn_mask, ctx);
        mfma_gemm<64, false, false><<<dim3(MROWS / 128, HDIM / 64), 256, 0, stream>>>(
            ctx, w_caout, ca_out_b + (size_t)l * HDIM, t2, MROWS, HDIM, HDIM);
        ln_kernel<false><<<MROWS, 256, 0, stream>>>(t2, h, ca_ln + (size_t)l * 2 * HDIM, crossb);

        // ---- output_1 ----
        mfma_gemm<64, false, false><<<dim3(MROWS / 128, HDIM / 64), 256, 0, stream>>>(
            attn1, w_o1, o1_b + (size_t)l * HDIM, t2, MROWS, HDIM, HDIM);
        ln_kernel<false><<<MROWS, 256, 0, stream>>>(t2, crossb, o1_ln + (size_t)l * 2 * HDIM, attn2);

        // ---- FFN ----
        mfma_gemm<128, true, true><<<dim3(MROWS / 128, FDIM / 128), 256, 0, stream>>>(
            attn2, w_ffn, ffn_b + (size_t)l * FDIM, tmp8b, MROWS, FDIM, HDIM);
        mfma_gemm<64, false, false><<<dim3(MROWS / 128, HDIM / 64), 256, 0, stream>>>(
            tmp8b, w_o2, o2_b + (size_t)l * HDIM, t2, MROWS, HDIM, FDIM);
        if (l == LNUM - 1)
            ln_kernel<true><<<MROWS, 256, 0, stream>>>(
                t2, attn2, o2_ln + (size_t)l * 2 * HDIM, (float*)d_out);
        else
            ln_kernel<false><<<MROWS, 256, 0, stream>>>(
                t2, attn2, o2_ln + (size_t)l * 2 * HDIM, h);
    }
}